// Round 20
// baseline (998.572 us; speedup 1.0000x reference)
//
#include <hip/hip_runtime.h>

#define VV 4
#define NN 4096
#define HH 128
#define CAP 64
#define GR 32            // rows per block in gemm2c
#define CHP (NN / GR)    // 128 column-sum partial chunks per view
#define FV 16            // rows per block in fusion v5

typedef __attribute__((ext_vector_type(4))) float fvec4;

// ---------------------------------------------------------------------------
// Kernel 1: scan dense adjacency -> per-row neighbor lists + dinv.
// (nontemporal; probed 38.8 us/rep L3-warm — closed)
// ---------------------------------------------------------------------------
__global__ __launch_bounds__(256) void k_build_csr(
    const float* __restrict__ adjs, int* __restrict__ nbr,
    int* __restrict__ cnt, float* __restrict__ dinv)
{
    int wave = threadIdx.x >> 6;
    int lane = threadIdx.x & 63;
    int r = blockIdx.x * 4 + wave;              // global row in [0, V*N)
    const fvec4* row = (const fvec4*)(adjs + (size_t)r * NN);
    int* out = nbr + (size_t)r * CAP;
    unsigned long long lm = (1ull << lane) - 1ull;
    int base = 0;
    #pragma unroll 4
    for (int c = 0; c < NN / 256; ++c) {
        fvec4 x = __builtin_nontemporal_load(&row[c * 64 + lane]);
        int c0 = (x.x != 0.f), c1 = (x.y != 0.f), c2 = (x.z != 0.f), c3 = (x.w != 0.f);
        unsigned long long b0 = __ballot(c0), b1 = __ballot(c1);
        unsigned long long b2 = __ballot(c2), b3 = __ballot(c3);
        int pos = base + __popcll(b0 & lm) + __popcll(b1 & lm)
                       + __popcll(b2 & lm) + __popcll(b3 & lm);
        int e = c * 256 + lane * 4;
        if (c0 && pos < CAP) out[pos] = e;     pos += c0;
        if (c1 && pos < CAP) out[pos] = e + 1; pos += c1;
        if (c2 && pos < CAP) out[pos] = e + 2; pos += c2;
        if (c3 && pos < CAP) out[pos] = e + 3; pos += c3;
        base += __popcll(b0) + __popcll(b1) + __popcll(b2) + __popcll(b3);
    }
    if (lane == 0) {
        cnt[r]  = base < CAP ? base : CAP;
        dinv[r] = rsqrtf((float)(base + 1));   // +1 self loop
    }
}

// ---------------------------------------------------------------------------
// Kernel 2: h1 = relu(A_norm @ w1 + b1). (measured 4.1 us)
// ---------------------------------------------------------------------------
__global__ __launch_bounds__(512) void k_spmm1(
    const float* __restrict__ w1, const float* __restrict__ b1,
    const int* __restrict__ nbr, const int* __restrict__ cnt,
    const float* __restrict__ dinv, float* __restrict__ h1)
{
    int xcd  = blockIdx.x & 7;
    int slot = blockIdx.x >> 3;
    int wid  = (xcd >> 1) * 1024 + slot * 2 + (xcd & 1);
    int g = threadIdx.x >> 7;
    int h = threadIdx.x & 127;
    int r = wid * 4 + g;
    int v = r >> 12;
    __shared__ int   s_j[4][CAP];
    __shared__ float s_w[4][CAP];
    int n = cnt[r];
    float dr = dinv[r];
    if (h < n) {
        int j = nbr[(size_t)r * CAP + h];
        s_j[g][h] = j;
        s_w[g][h] = dinv[v * NN + j];
    }
    __syncthreads();
    float acc = dr * w1[(size_t)r * HH + h];
    #pragma unroll 4
    for (int k = 0; k < n; ++k)
        acc += s_w[g][k] * w1[((size_t)(v * NN + s_j[g][k])) * HH + h];
    float val = dr * acc + b1[v * HH + h];
    h1[(size_t)r * HH + h] = val > 0.f ? val : 0.f;
}

// ---------------------------------------------------------------------------
// Kernel 3a: u = A_norm @ h1 (gather only). Templated for probe.
// ---------------------------------------------------------------------------
template<int REPS>
__global__ __launch_bounds__(512) void k_gather2(
    const float* __restrict__ h1, const int* __restrict__ nbr,
    const int* __restrict__ cnt, const float* __restrict__ dinv,
    float* __restrict__ u)
{
    int xcd  = blockIdx.x & 7;
    int slot = blockIdx.x >> 3;
    int wid  = (xcd >> 1) * 1024 + slot * 2 + (xcd & 1);
    int g = threadIdx.x >> 7;
    int h = threadIdx.x & 127;
    int r = wid * 4 + g;
    int v = r >> 12;
    __shared__ int   s_j[4][CAP];
    __shared__ float s_w[4][CAP];
    for (int rep = 0; rep < REPS; ++rep) {
        int n = cnt[r];
        float dr = dinv[r];
        if (h < n) {
            int j = nbr[(size_t)r * CAP + h];
            s_j[g][h] = j;
            s_w[g][h] = dinv[v * NN + j];
        }
        __syncthreads();
        float acc = dr * h1[(size_t)r * HH + h];
        #pragma unroll 4
        for (int k = 0; k < n; ++k)
            acc += s_w[g][k] * h1[((size_t)(v * NN + s_j[g][k])) * HH + h];
        u[(size_t)r * HH + h] = dr * acc;
        __syncthreads();
    }
}

// ---------------------------------------------------------------------------
// Kernel 3b: h2 = relu(u @ w2 + b2) + per-block column partial sums.
// Templated for probe.
// ---------------------------------------------------------------------------
template<int REPS>
__global__ __launch_bounds__(256) void k_gemm2c(
    const float* __restrict__ u, const float* __restrict__ w2,
    const float* __restrict__ b2, float* __restrict__ h2,
    float* __restrict__ part)
{
    const int bpv = NN / GR;            // 128
    int v = blockIdx.x / bpv;
    int rbase_g = blockIdx.x * GR;      // first global row
    __shared__ float s_u[GR][HH];       // 16 KB
    __shared__ float s_p[8][HH];        // 4 KB
    for (int rep = 0; rep < REPS; ++rep) {
        const float4* src = (const float4*)(u + (size_t)rbase_g * HH);
        for (int idx = threadIdx.x; idx < GR * HH / 4; idx += 256)
            ((float4*)s_u)[idx] = src[idx];
        __syncthreads();

        int r0 = (threadIdx.x >> 5) * 4;          // 0..28
        int c0 = (threadIdx.x & 31) * 4;          // 0..124
        const float* wv = w2 + (size_t)v * HH * HH;
        float acc[4][4];
        #pragma unroll
        for (int i = 0; i < 4; ++i)
            #pragma unroll
            for (int j = 0; j < 4; ++j) acc[i][j] = 0.f;
        for (int k = 0; k < HH; k += 4) {
            float4 a[4], w[4];
            #pragma unroll
            for (int i = 0; i < 4; ++i) a[i] = *(const float4*)&s_u[r0 + i][k];
            #pragma unroll
            for (int kk = 0; kk < 4; ++kk) w[kk] = *(const float4*)&wv[(size_t)(k + kk) * HH + c0];
            #pragma unroll
            for (int i = 0; i < 4; ++i)
                #pragma unroll
                for (int j = 0; j < 4; ++j) {
                    acc[i][j] += a[i].x * ((const float*)&w[0])[j];
                    acc[i][j] += a[i].y * ((const float*)&w[1])[j];
                    acc[i][j] += a[i].z * ((const float*)&w[2])[j];
                    acc[i][j] += a[i].w * ((const float*)&w[3])[j];
                }
        }
        float p[4];
        #pragma unroll
        for (int j = 0; j < 4; ++j) {
            float b = b2[v * HH + c0 + j];
            float s = 0.f;
            #pragma unroll
            for (int i = 0; i < 4; ++i) {
                float val = acc[i][j] + b;
                val = val > 0.f ? val : 0.f;
                acc[i][j] = val;
                s += val;
            }
            p[j] = s;
        }
        float* dst = h2 + (size_t)rbase_g * HH;
        #pragma unroll
        for (int i = 0; i < 4; ++i) {
            float4 o = { acc[i][0], acc[i][1], acc[i][2], acc[i][3] };
            *(float4*)&dst[(size_t)(r0 + i) * HH + c0] = o;
        }
        *(float4*)&s_p[threadIdx.x >> 5][c0] = *(float4*)p;
        __syncthreads();
        if (threadIdx.x < HH) {
            float a = 0.f;
            #pragma unroll
            for (int q = 0; q < 8; ++q) a += s_p[q][threadIdx.x];
            part[(size_t)blockIdx.x * HH + threadIdx.x] = a;
        }
        __syncthreads();
    }
}

// ---------------------------------------------------------------------------
// Kernel 4: finish summaries, attention MLP, softmax. (measured 4.9 us)
// ---------------------------------------------------------------------------
__global__ __launch_bounds__(512) void k_attn(
    const float* __restrict__ part, const float* __restrict__ wa1,
    const float* __restrict__ ba1, const float* __restrict__ wa2,
    const float* __restrict__ ba2, float* __restrict__ attn_out,
    float* __restrict__ attn_ws)
{
    __shared__ float s_sum[VV * HH];
    __shared__ float s_red[256];
    __shared__ float s_score[VV];
    {
        int v = threadIdx.x >> 7, h = threadIdx.x & 127;
        float a = 0.f;
        #pragma unroll 8
        for (int c = 0; c < CHP; ++c) a += part[(size_t)(v * CHP + c) * HH + h];
        s_sum[v * HH + h] = a * (1.0f / NN);
    }
    __syncthreads();
    if (threadIdx.x < 256) {
        int v = threadIdx.x >> 6, u = threadIdx.x & 63;
        float a = ba1[u];
        for (int k = 0; k < HH; ++k) a += s_sum[v * HH + k] * wa1[k * 64 + u];
        s_red[threadIdx.x] = tanhf(a) * wa2[u];
    }
    __syncthreads();
    if (threadIdx.x < VV) {
        float sc = ba2[0];
        for (int uu = 0; uu < 64; ++uu) sc += s_red[threadIdx.x * 64 + uu];
        s_score[threadIdx.x] = sc;
    }
    __syncthreads();
    if (threadIdx.x == 0) {
        float m = s_score[0];
        for (int i = 1; i < VV; ++i) m = fmaxf(m, s_score[i]);
        float e[VV], den = 0.f;
        for (int i = 0; i < VV; ++i) { e[i] = __expf(s_score[i] - m); den += e[i]; }
        for (int i = 0; i < VV; ++i) {
            float av = e[i] / den;
            attn_out[i] = av;
            attn_ws[i]  = av;
        }
    }
}

// ---------------------------------------------------------------------------
// Kernel 5: fusion MLP v5 — RESTORED (best measured: 28.7 us; v6/v7 refuted).
// ---------------------------------------------------------------------------
__global__ __launch_bounds__(512) void k_fusion5(
    const float* __restrict__ h2, const float* __restrict__ attn_ws,
    const float* __restrict__ wf1, const float* __restrict__ bf1,
    const float* __restrict__ wf2, const float* __restrict__ bf2,
    float* __restrict__ fused)
{
    __shared__ float s_in[FV][516];          // 33 KB
    __shared__ float s_pt[4][FV][256];       // 64 KB
    __shared__ float s_hid[FV][260];         // 16.6 KB
    float (*s_p2)[FV][128] = (float (*)[FV][128])&s_pt[0][0][0];

    int nbase = blockIdx.x * FV;
    int wv   = threadIdx.x >> 6;
    int lane = threadIdx.x & 63;
    int rh = wv & 1;
    int ks = wv >> 1;

    float at[VV];
    #pragma unroll
    for (int v = 0; v < VV; ++v) at[v] = attn_ws[v];

    for (int idx = threadIdx.x; idx < FV * 128; idx += 512) {
        int r = idx >> 7, c4 = idx & 127, v = c4 >> 5, h4 = c4 & 31;
        const float4* srcr = (const float4*)(h2 + ((size_t)v * NN + nbase + r) * HH);
        float4 x = srcr[h4];
        float s = at[v];
        x.x *= s; x.y *= s; x.z *= s; x.w *= s;
        *(float4*)&s_in[r][c4 * 4] = x;
    }
    __syncthreads();

    {
        int col = lane * 4;
        int r0  = rh * 8;
        int k0  = ks * 128;
        float acc[8][4];
        #pragma unroll
        for (int i = 0; i < 8; ++i) { acc[i][0] = acc[i][1] = acc[i][2] = acc[i][3] = 0.f; }
        const float* wrow = wf1 + (size_t)k0 * 256 + col;
        for (int kk = 0; kk < 128; kk += 4) {
            float4 w0 = *(const float4*)(wrow);
            float4 w1 = *(const float4*)(wrow + 256);
            float4 w2 = *(const float4*)(wrow + 512);
            float4 w3 = *(const float4*)(wrow + 768);
            wrow += 1024;
            #pragma unroll
            for (int i = 0; i < 8; ++i) {
                float4 a = *(const float4*)&s_in[r0 + i][k0 + kk];
                acc[i][0] += a.x * w0.x + a.y * w1.x + a.z * w2.x + a.w * w3.x;
                acc[i][1] += a.x * w0.y + a.y * w1.y + a.z * w2.y + a.w * w3.y;
                acc[i][2] += a.x * w0.z + a.y * w1.z + a.z * w2.z + a.w * w3.z;
                acc[i][3] += a.x * w0.w + a.y * w1.w + a.z * w2.w + a.w * w3.w;
            }
        }
        #pragma unroll
        for (int i = 0; i < 8; ++i)
            *(float4*)&s_pt[ks][r0 + i][col] = *(float4*)&acc[i][0];
    }
    __syncthreads();

    {
        int c0 = (threadIdx.x & 63) * 4;
        int rr = threadIdx.x >> 6;
        #pragma unroll
        for (int p = 0; p < 2; ++p) {
            int row = p * 8 + rr;
            float4 s0 = *(float4*)&s_pt[0][row][c0];
            float4 s1 = *(float4*)&s_pt[1][row][c0];
            float4 s2 = *(float4*)&s_pt[2][row][c0];
            float4 s3 = *(float4*)&s_pt[3][row][c0];
            float4 b  = *(const float4*)&bf1[c0];
            float4 o;
            o.x = s0.x + s1.x + s2.x + s3.x + b.x;
            o.y = s0.y + s1.y + s2.y + s3.y + b.y;
            o.z = s0.z + s1.z + s2.z + s3.z + b.z;
            o.w = s0.w + s1.w + s2.w + s3.w + b.w;
            o.x = o.x > 0.f ? o.x : 0.f;
            o.y = o.y > 0.f ? o.y : 0.f;
            o.z = o.z > 0.f ? o.z : 0.f;
            o.w = o.w > 0.f ? o.w : 0.f;
            *(float4*)&s_hid[row][c0] = o;
        }
    }
    __syncthreads();

    {
        int col = lane * 2;
        int r0  = rh * 8;
        int k0  = ks * 64;
        float acc[8][2];
        #pragma unroll
        for (int i = 0; i < 8; ++i) { acc[i][0] = 0.f; acc[i][1] = 0.f; }
        const float* wrow = wf2 + (size_t)k0 * 128 + col;
        for (int kk = 0; kk < 64; kk += 4) {
            float2 w0 = *(const float2*)(wrow);
            float2 w1 = *(const float2*)(wrow + 128);
            float2 w2 = *(const float2*)(wrow + 256);
            float2 w3 = *(const float2*)(wrow + 384);
            wrow += 512;
            #pragma unroll
            for (int i = 0; i < 8; ++i) {
                float4 a = *(const float4*)&s_hid[r0 + i][k0 + kk];
                acc[i][0] += a.x * w0.x + a.y * w1.x + a.z * w2.x + a.w * w3.x;
                acc[i][1] += a.x * w0.y + a.y * w1.y + a.z * w2.y + a.w * w3.y;
            }
        }
        #pragma unroll
        for (int i = 0; i < 8; ++i)
            *(float2*)&s_p2[ks][r0 + i][col] = *(float2*)&acc[i][0];
    }
    __syncthreads();

    {
        int c0  = (threadIdx.x & 31) * 4;
        int row = threadIdx.x >> 5;
        float4 s0 = *(float4*)&s_p2[0][row][c0];
        float4 s1 = *(float4*)&s_p2[1][row][c0];
        float4 s2 = *(float4*)&s_p2[2][row][c0];
        float4 s3 = *(float4*)&s_p2[3][row][c0];
        float4 b  = *(const float4*)&bf2[c0];
        float4 o;
        o.x = s0.x + s1.x + s2.x + s3.x + b.x;
        o.y = s0.y + s1.y + s2.y + s3.y + b.y;
        o.z = s0.z + s1.z + s2.z + s3.z + b.z;
        o.w = s0.w + s1.w + s2.w + s3.w + b.w;
        *(float4*)&fused[(size_t)(nbase + row) * HH + c0] = o;
    }
}

// ---------------------------------------------------------------------------
// ROUND: pipeline reverted to best-known (R14: v5 fusion). Probes: gather2 x40
// and gemm2c x64 — pin the split-layer2 components directly.
// ---------------------------------------------------------------------------
extern "C" void kernel_launch(void* const* d_in, const int* in_sizes, int n_in,
                              void* d_out, int out_size, void* d_ws, size_t ws_size,
                              hipStream_t stream)
{
    const float* adjs = (const float*)d_in[0];
    const float* w1   = (const float*)d_in[1];
    const float* b1   = (const float*)d_in[2];
    const float* w2   = (const float*)d_in[3];
    const float* b2   = (const float*)d_in[4];
    const float* wa1  = (const float*)d_in[5];
    const float* ba1  = (const float*)d_in[6];
    const float* wa2  = (const float*)d_in[7];
    const float* ba2  = (const float*)d_in[8];
    const float* wf1  = (const float*)d_in[9];
    const float* bf1  = (const float*)d_in[10];
    const float* wf2  = (const float*)d_in[11];
    const float* bf2  = (const float*)d_in[12];

    float* out   = (float*)d_out;
    float* fused = out;                        // [N, 128]
    float* attn  = out + (size_t)NN * HH;      // [V]
    float* h2    = attn + VV;                  // [V, N, H]

    char* w = (char*)d_ws;
    int*   nbr    = (int*)w;    w += (size_t)VV * NN * CAP * sizeof(int);
    int*   cnt    = (int*)w;    w += (size_t)VV * NN * sizeof(int);
    float* dinv   = (float*)w;  w += (size_t)VV * NN * sizeof(float);
    float* h1     = (float*)w;  w += (size_t)VV * NN * HH * sizeof(float);
    float* u      = (float*)w;  w += (size_t)VV * NN * HH * sizeof(float);
    float* part   = (float*)w;  w += (size_t)VV * CHP * HH * sizeof(float);
    float* attnws = (float*)w;  w += 256;
    // probe sinks
    float* u_s    = (float*)w;  w += (size_t)VV * NN * HH * sizeof(float);
    float* h2_s   = (float*)w;  w += (size_t)VV * NN * HH * sizeof(float);
    float* part_s = (float*)w;  w += (size_t)VV * CHP * HH * sizeof(float);

    // ---- pipeline (R14 config: best known, 128.9 us) ----
    k_build_csr<<<VV * NN / 4, 256, 0, stream>>>(adjs, nbr, cnt, dinv);
    k_spmm1<<<VV * NN / 4, 512, 0, stream>>>(w1, b1, nbr, cnt, dinv, h1);
    k_gather2<1><<<VV * NN / 4, 512, 0, stream>>>(h1, nbr, cnt, dinv, u);
    k_gemm2c<1><<<VV * NN / GR, 256, 0, stream>>>(u, w2, b2, h2, part);
    k_attn<<<1, 512, 0, stream>>>(part, wa1, ba1, wa2, ba2, attn, attnws);
    k_fusion5<<<NN / FV, 512, 0, stream>>>(h2, attnws, wf1, bf1, wf2, bf2, fused);

    // ---- probes (read pipeline buffers; write ws sinks) ----
    k_gather2<40><<<VV * NN / 4, 512, 0, stream>>>(h1, nbr, cnt, dinv, u_s);
    k_gemm2c<64><<<VV * NN / GR, 256, 0, stream>>>(u, w2, b2, h2_s, part_s);
}

// Round 21
// 135.490 us; speedup vs baseline: 7.3701x; 7.3701x over previous
//
#include <hip/hip_runtime.h>

#define VV 4
#define NN 4096
#define HH 128
#define CAP 64
#define GR 16            // rows per block in gemm2c (v2: grid 1024 -> 4 blk/CU)
#define CHP (NN / GR)    // 256 column-sum partial chunks per view
#define FV 16            // rows per block in fusion v5

typedef __attribute__((ext_vector_type(4))) float fvec4;

// ---------------------------------------------------------------------------
// Kernel 1: scan dense adjacency -> per-row neighbor lists + dinv.
// (nontemporal; probed 38.8 us/rep L3-warm — closed)
// ---------------------------------------------------------------------------
__global__ __launch_bounds__(256) void k_build_csr(
    const float* __restrict__ adjs, int* __restrict__ nbr,
    int* __restrict__ cnt, float* __restrict__ dinv)
{
    int wave = threadIdx.x >> 6;
    int lane = threadIdx.x & 63;
    int r = blockIdx.x * 4 + wave;              // global row in [0, V*N)
    const fvec4* row = (const fvec4*)(adjs + (size_t)r * NN);
    int* out = nbr + (size_t)r * CAP;
    unsigned long long lm = (1ull << lane) - 1ull;
    int base = 0;
    #pragma unroll 4
    for (int c = 0; c < NN / 256; ++c) {
        fvec4 x = __builtin_nontemporal_load(&row[c * 64 + lane]);
        int c0 = (x.x != 0.f), c1 = (x.y != 0.f), c2 = (x.z != 0.f), c3 = (x.w != 0.f);
        unsigned long long b0 = __ballot(c0), b1 = __ballot(c1);
        unsigned long long b2 = __ballot(c2), b3 = __ballot(c3);
        int pos = base + __popcll(b0 & lm) + __popcll(b1 & lm)
                       + __popcll(b2 & lm) + __popcll(b3 & lm);
        int e = c * 256 + lane * 4;
        if (c0 && pos < CAP) out[pos] = e;     pos += c0;
        if (c1 && pos < CAP) out[pos] = e + 1; pos += c1;
        if (c2 && pos < CAP) out[pos] = e + 2; pos += c2;
        if (c3 && pos < CAP) out[pos] = e + 3; pos += c3;
        base += __popcll(b0) + __popcll(b1) + __popcll(b2) + __popcll(b3);
    }
    if (lane == 0) {
        cnt[r]  = base < CAP ? base : CAP;
        dinv[r] = rsqrtf((float)(base + 1));   // +1 self loop
    }
}

// ---------------------------------------------------------------------------
// Kernel 2: h1 = relu(A_norm @ w1 + b1). (measured 4.1 us)
// ---------------------------------------------------------------------------
__global__ __launch_bounds__(512) void k_spmm1(
    const float* __restrict__ w1, const float* __restrict__ b1,
    const int* __restrict__ nbr, const int* __restrict__ cnt,
    const float* __restrict__ dinv, float* __restrict__ h1)
{
    int xcd  = blockIdx.x & 7;
    int slot = blockIdx.x >> 3;
    int wid  = (xcd >> 1) * 1024 + slot * 2 + (xcd & 1);
    int g = threadIdx.x >> 7;
    int h = threadIdx.x & 127;
    int r = wid * 4 + g;
    int v = r >> 12;
    __shared__ int   s_j[4][CAP];
    __shared__ float s_w[4][CAP];
    int n = cnt[r];
    float dr = dinv[r];
    if (h < n) {
        int j = nbr[(size_t)r * CAP + h];
        s_j[g][h] = j;
        s_w[g][h] = dinv[v * NN + j];
    }
    __syncthreads();
    float acc = dr * w1[(size_t)r * HH + h];
    #pragma unroll 4
    for (int k = 0; k < n; ++k)
        acc += s_w[g][k] * w1[((size_t)(v * NN + s_j[g][k])) * HH + h];
    float val = dr * acc + b1[v * HH + h];
    h1[(size_t)r * HH + h] = val > 0.f ? val : 0.f;
}

// ---------------------------------------------------------------------------
// Kernel 3a: u = A_norm @ h1 (gather only). (measured 5.2 us)
// ---------------------------------------------------------------------------
__global__ __launch_bounds__(512) void k_gather2(
    const float* __restrict__ h1, const int* __restrict__ nbr,
    const int* __restrict__ cnt, const float* __restrict__ dinv,
    float* __restrict__ u)
{
    int xcd  = blockIdx.x & 7;
    int slot = blockIdx.x >> 3;
    int wid  = (xcd >> 1) * 1024 + slot * 2 + (xcd & 1);
    int g = threadIdx.x >> 7;
    int h = threadIdx.x & 127;
    int r = wid * 4 + g;
    int v = r >> 12;
    __shared__ int   s_j[4][CAP];
    __shared__ float s_w[4][CAP];
    int n = cnt[r];
    float dr = dinv[r];
    if (h < n) {
        int j = nbr[(size_t)r * CAP + h];
        s_j[g][h] = j;
        s_w[g][h] = dinv[v * NN + j];
    }
    __syncthreads();
    float acc = dr * h1[(size_t)r * HH + h];
    #pragma unroll 4
    for (int k = 0; k < n; ++k)
        acc += s_w[g][k] * h1[((size_t)(v * NN + s_j[g][k])) * HH + h];
    u[(size_t)r * HH + h] = dr * acc;
}

// ---------------------------------------------------------------------------
// Kernel 3b v2: h2 = relu(u @ w2 + b2) + per-block column partial sums.
// GR=16 -> grid 1024 = 4 blocks/CU (was 2, grid-limited at 21.7% occupancy).
// 2 rows/thread (acc[2][4]); 12 KB LDS.
// ---------------------------------------------------------------------------
__global__ __launch_bounds__(256) void k_gemm2c(
    const float* __restrict__ u, const float* __restrict__ w2,
    const float* __restrict__ b2, float* __restrict__ h2,
    float* __restrict__ part)
{
    const int bpv = NN / GR;            // 256
    int v = blockIdx.x / bpv;
    int rbase_g = blockIdx.x * GR;      // first global row
    __shared__ float s_u[GR][HH];       // 8 KB
    __shared__ float s_p[8][HH];        // 4 KB
    const float4* src = (const float4*)(u + (size_t)rbase_g * HH);
    for (int idx = threadIdx.x; idx < GR * HH / 4; idx += 256)
        ((float4*)s_u)[idx] = src[idx];
    __syncthreads();

    int r0 = (threadIdx.x >> 5) * 2;          // 0..14
    int c0 = (threadIdx.x & 31) * 4;          // 0..124
    const float* wv = w2 + (size_t)v * HH * HH;
    float acc[2][4];
    #pragma unroll
    for (int i = 0; i < 2; ++i)
        #pragma unroll
        for (int j = 0; j < 4; ++j) acc[i][j] = 0.f;
    for (int k = 0; k < HH; k += 4) {
        float4 a[2], w[4];
        #pragma unroll
        for (int i = 0; i < 2; ++i) a[i] = *(const float4*)&s_u[r0 + i][k];
        #pragma unroll
        for (int kk = 0; kk < 4; ++kk) w[kk] = *(const float4*)&wv[(size_t)(k + kk) * HH + c0];
        #pragma unroll
        for (int i = 0; i < 2; ++i)
            #pragma unroll
            for (int j = 0; j < 4; ++j) {
                acc[i][j] += a[i].x * ((const float*)&w[0])[j];
                acc[i][j] += a[i].y * ((const float*)&w[1])[j];
                acc[i][j] += a[i].z * ((const float*)&w[2])[j];
                acc[i][j] += a[i].w * ((const float*)&w[3])[j];
            }
    }
    float p[4];
    #pragma unroll
    for (int j = 0; j < 4; ++j) {
        float b = b2[v * HH + c0 + j];
        float s = 0.f;
        #pragma unroll
        for (int i = 0; i < 2; ++i) {
            float val = acc[i][j] + b;
            val = val > 0.f ? val : 0.f;
            acc[i][j] = val;
            s += val;
        }
        p[j] = s;
    }
    float* dst = h2 + (size_t)rbase_g * HH;
    #pragma unroll
    for (int i = 0; i < 2; ++i) {
        float4 o = { acc[i][0], acc[i][1], acc[i][2], acc[i][3] };
        *(float4*)&dst[(size_t)(r0 + i) * HH + c0] = o;
    }
    *(float4*)&s_p[threadIdx.x >> 5][c0] = *(float4*)p;
    __syncthreads();
    if (threadIdx.x < HH) {
        float a = 0.f;
        #pragma unroll
        for (int q = 0; q < 8; ++q) a += s_p[q][threadIdx.x];
        part[(size_t)blockIdx.x * HH + threadIdx.x] = a;
    }
}

// ---------------------------------------------------------------------------
// Kernel 4: finish summaries, attention MLP, softmax. (measured 4.9 us)
// ---------------------------------------------------------------------------
__global__ __launch_bounds__(512) void k_attn(
    const float* __restrict__ part, const float* __restrict__ wa1,
    const float* __restrict__ ba1, const float* __restrict__ wa2,
    const float* __restrict__ ba2, float* __restrict__ attn_out,
    float* __restrict__ attn_ws)
{
    __shared__ float s_sum[VV * HH];
    __shared__ float s_red[256];
    __shared__ float s_score[VV];
    {
        int v = threadIdx.x >> 7, h = threadIdx.x & 127;
        float a = 0.f;
        #pragma unroll 8
        for (int c = 0; c < CHP; ++c) a += part[(size_t)(v * CHP + c) * HH + h];
        s_sum[v * HH + h] = a * (1.0f / NN);
    }
    __syncthreads();
    if (threadIdx.x < 256) {
        int v = threadIdx.x >> 6, u = threadIdx.x & 63;
        float a = ba1[u];
        for (int k = 0; k < HH; ++k) a += s_sum[v * HH + k] * wa1[k * 64 + u];
        s_red[threadIdx.x] = tanhf(a) * wa2[u];
    }
    __syncthreads();
    if (threadIdx.x < VV) {
        float sc = ba2[0];
        for (int uu = 0; uu < 64; ++uu) sc += s_red[threadIdx.x * 64 + uu];
        s_score[threadIdx.x] = sc;
    }
    __syncthreads();
    if (threadIdx.x == 0) {
        float m = s_score[0];
        for (int i = 1; i < VV; ++i) m = fmaxf(m, s_score[i]);
        float e[VV], den = 0.f;
        for (int i = 0; i < VV; ++i) { e[i] = __expf(s_score[i] - m); den += e[i]; }
        for (int i = 0; i < VV; ++i) {
            float av = e[i] / den;
            attn_out[i] = av;
            attn_ws[i]  = av;
        }
    }
}

// ---------------------------------------------------------------------------
// Kernel 5: fusion MLP v5 (best measured: 28.7 us; v3/v6/v7 levers refuted).
// ---------------------------------------------------------------------------
__global__ __launch_bounds__(512) void k_fusion5(
    const float* __restrict__ h2, const float* __restrict__ attn_ws,
    const float* __restrict__ wf1, const float* __restrict__ bf1,
    const float* __restrict__ wf2, const float* __restrict__ bf2,
    float* __restrict__ fused)
{
    __shared__ float s_in[FV][516];          // 33 KB
    __shared__ float s_pt[4][FV][256];       // 64 KB
    __shared__ float s_hid[FV][260];         // 16.6 KB
    float (*s_p2)[FV][128] = (float (*)[FV][128])&s_pt[0][0][0];

    int nbase = blockIdx.x * FV;
    int wv   = threadIdx.x >> 6;
    int lane = threadIdx.x & 63;
    int rh = wv & 1;
    int ks = wv >> 1;

    float at[VV];
    #pragma unroll
    for (int v = 0; v < VV; ++v) at[v] = attn_ws[v];

    for (int idx = threadIdx.x; idx < FV * 128; idx += 512) {
        int r = idx >> 7, c4 = idx & 127, v = c4 >> 5, h4 = c4 & 31;
        const float4* srcr = (const float4*)(h2 + ((size_t)v * NN + nbase + r) * HH);
        float4 x = srcr[h4];
        float s = at[v];
        x.x *= s; x.y *= s; x.z *= s; x.w *= s;
        *(float4*)&s_in[r][c4 * 4] = x;
    }
    __syncthreads();

    {
        int col = lane * 4;
        int r0  = rh * 8;
        int k0  = ks * 128;
        float acc[8][4];
        #pragma unroll
        for (int i = 0; i < 8; ++i) { acc[i][0] = acc[i][1] = acc[i][2] = acc[i][3] = 0.f; }
        const float* wrow = wf1 + (size_t)k0 * 256 + col;
        for (int kk = 0; kk < 128; kk += 4) {
            float4 w0 = *(const float4*)(wrow);
            float4 w1 = *(const float4*)(wrow + 256);
            float4 w2 = *(const float4*)(wrow + 512);
            float4 w3 = *(const float4*)(wrow + 768);
            wrow += 1024;
            #pragma unroll
            for (int i = 0; i < 8; ++i) {
                float4 a = *(const float4*)&s_in[r0 + i][k0 + kk];
                acc[i][0] += a.x * w0.x + a.y * w1.x + a.z * w2.x + a.w * w3.x;
                acc[i][1] += a.x * w0.y + a.y * w1.y + a.z * w2.y + a.w * w3.y;
                acc[i][2] += a.x * w0.z + a.y * w1.z + a.z * w2.z + a.w * w3.z;
                acc[i][3] += a.x * w0.w + a.y * w1.w + a.z * w2.w + a.w * w3.w;
            }
        }
        #pragma unroll
        for (int i = 0; i < 8; ++i)
            *(float4*)&s_pt[ks][r0 + i][col] = *(float4*)&acc[i][0];
    }
    __syncthreads();

    {
        int c0 = (threadIdx.x & 63) * 4;
        int rr = threadIdx.x >> 6;
        #pragma unroll
        for (int p = 0; p < 2; ++p) {
            int row = p * 8 + rr;
            float4 s0 = *(float4*)&s_pt[0][row][c0];
            float4 s1 = *(float4*)&s_pt[1][row][c0];
            float4 s2 = *(float4*)&s_pt[2][row][c0];
            float4 s3 = *(float4*)&s_pt[3][row][c0];
            float4 b  = *(const float4*)&bf1[c0];
            float4 o;
            o.x = s0.x + s1.x + s2.x + s3.x + b.x;
            o.y = s0.y + s1.y + s2.y + s3.y + b.y;
            o.z = s0.z + s1.z + s2.z + s3.z + b.z;
            o.w = s0.w + s1.w + s2.w + s3.w + b.w;
            o.x = o.x > 0.f ? o.x : 0.f;
            o.y = o.y > 0.f ? o.y : 0.f;
            o.z = o.z > 0.f ? o.z : 0.f;
            o.w = o.w > 0.f ? o.w : 0.f;
            *(float4*)&s_hid[row][c0] = o;
        }
    }
    __syncthreads();

    {
        int col = lane * 2;
        int r0  = rh * 8;
        int k0  = ks * 64;
        float acc[8][2];
        #pragma unroll
        for (int i = 0; i < 8; ++i) { acc[i][0] = 0.f; acc[i][1] = 0.f; }
        const float* wrow = wf2 + (size_t)k0 * 128 + col;
        for (int kk = 0; kk < 64; kk += 4) {
            float2 w0 = *(const float2*)(wrow);
            float2 w1 = *(const float2*)(wrow + 128);
            float2 w2 = *(const float2*)(wrow + 256);
            float2 w3 = *(const float2*)(wrow + 384);
            wrow += 512;
            #pragma unroll
            for (int i = 0; i < 8; ++i) {
                float4 a = *(const float4*)&s_hid[r0 + i][k0 + kk];
                acc[i][0] += a.x * w0.x + a.y * w1.x + a.z * w2.x + a.w * w3.x;
                acc[i][1] += a.x * w0.y + a.y * w1.y + a.z * w2.y + a.w * w3.y;
            }
        }
        #pragma unroll
        for (int i = 0; i < 8; ++i)
            *(float2*)&s_p2[ks][r0 + i][col] = *(float2*)&acc[i][0];
    }
    __syncthreads();

    {
        int c0  = (threadIdx.x & 31) * 4;
        int row = threadIdx.x >> 5;
        float4 s0 = *(float4*)&s_p2[0][row][c0];
        float4 s1 = *(float4*)&s_p2[1][row][c0];
        float4 s2 = *(float4*)&s_p2[2][row][c0];
        float4 s3 = *(float4*)&s_p2[3][row][c0];
        float4 b  = *(const float4*)&bf2[c0];
        float4 o;
        o.x = s0.x + s1.x + s2.x + s3.x + b.x;
        o.y = s0.y + s1.y + s2.y + s3.y + b.y;
        o.z = s0.z + s1.z + s2.z + s3.z + b.z;
        o.w = s0.w + s1.w + s2.w + s3.w + b.w;
        *(float4*)&fused[(size_t)(nbase + row) * HH + c0] = o;
    }
}

// ---------------------------------------------------------------------------
// CLEAN ROUND: gemm2c GR 32->16 (grid-limited occupancy fix). One lever.
// ---------------------------------------------------------------------------
extern "C" void kernel_launch(void* const* d_in, const int* in_sizes, int n_in,
                              void* d_out, int out_size, void* d_ws, size_t ws_size,
                              hipStream_t stream)
{
    const float* adjs = (const float*)d_in[0];
    const float* w1   = (const float*)d_in[1];
    const float* b1   = (const float*)d_in[2];
    const float* w2   = (const float*)d_in[3];
    const float* b2   = (const float*)d_in[4];
    const float* wa1  = (const float*)d_in[5];
    const float* ba1  = (const float*)d_in[6];
    const float* wa2  = (const float*)d_in[7];
    const float* ba2  = (const float*)d_in[8];
    const float* wf1  = (const float*)d_in[9];
    const float* bf1  = (const float*)d_in[10];
    const float* wf2  = (const float*)d_in[11];
    const float* bf2  = (const float*)d_in[12];

    float* out   = (float*)d_out;
    float* fused = out;                        // [N, 128]
    float* attn  = out + (size_t)NN * HH;      // [V]
    float* h2    = attn + VV;                  // [V, N, H]

    char* w = (char*)d_ws;
    int*   nbr    = (int*)w;    w += (size_t)VV * NN * CAP * sizeof(int);
    int*   cnt    = (int*)w;    w += (size_t)VV * NN * sizeof(int);
    float* dinv   = (float*)w;  w += (size_t)VV * NN * sizeof(float);
    float* h1     = (float*)w;  w += (size_t)VV * NN * HH * sizeof(float);
    float* u      = (float*)w;  w += (size_t)VV * NN * HH * sizeof(float);
    float* part   = (float*)w;  w += (size_t)VV * CHP * HH * sizeof(float);
    float* attnws = (float*)w;  w += 256;

    k_build_csr<<<VV * NN / 4, 256, 0, stream>>>(adjs, nbr, cnt, dinv);
    k_spmm1<<<VV * NN / 4, 512, 0, stream>>>(w1, b1, nbr, cnt, dinv, h1);
    k_gather2<<<VV * NN / 4, 512, 0, stream>>>(h1, nbr, cnt, dinv, u);
    k_gemm2c<<<VV * NN / GR, 256, 0, stream>>>(u, w2, b2, h2, part);
    k_attn<<<1, 512, 0, stream>>>(part, wa1, ba1, wa2, ba2, attn, attnws);
    k_fusion5<<<NN / FV, 512, 0, stream>>>(h2, attnws, wf1, bf1, wf2, bf2, fused);
}

// Round 22
// 129.623 us; speedup vs baseline: 7.7037x; 1.0453x over previous
//
#include <hip/hip_runtime.h>

#define VV 4
#define NN 4096
#define HH 128
#define CAP 64
#define GR 32            // rows per block in gemm2c (in-pipeline best)
#define CHP (NN / GR)    // 128 column-sum partial chunks per view
#define FV 16            // rows per block in fusion v5

typedef __attribute__((ext_vector_type(4))) float fvec4;

// ---------------------------------------------------------------------------
// Kernel 1: scan dense adjacency -> per-row neighbor lists + dinv.
// (nontemporal; probed 38.8 us/rep; HBM/L3 stream floor — closed)
// ---------------------------------------------------------------------------
__global__ __launch_bounds__(256) void k_build_csr(
    const float* __restrict__ adjs, int* __restrict__ nbr,
    int* __restrict__ cnt, float* __restrict__ dinv)
{
    int wave = threadIdx.x >> 6;
    int lane = threadIdx.x & 63;
    int r = blockIdx.x * 4 + wave;              // global row in [0, V*N)
    const fvec4* row = (const fvec4*)(adjs + (size_t)r * NN);
    int* out = nbr + (size_t)r * CAP;
    unsigned long long lm = (1ull << lane) - 1ull;
    int base = 0;
    #pragma unroll 4
    for (int c = 0; c < NN / 256; ++c) {
        fvec4 x = __builtin_nontemporal_load(&row[c * 64 + lane]);
        int c0 = (x.x != 0.f), c1 = (x.y != 0.f), c2 = (x.z != 0.f), c3 = (x.w != 0.f);
        unsigned long long b0 = __ballot(c0), b1 = __ballot(c1);
        unsigned long long b2 = __ballot(c2), b3 = __ballot(c3);
        int pos = base + __popcll(b0 & lm) + __popcll(b1 & lm)
                       + __popcll(b2 & lm) + __popcll(b3 & lm);
        int e = c * 256 + lane * 4;
        if (c0 && pos < CAP) out[pos] = e;     pos += c0;
        if (c1 && pos < CAP) out[pos] = e + 1; pos += c1;
        if (c2 && pos < CAP) out[pos] = e + 2; pos += c2;
        if (c3 && pos < CAP) out[pos] = e + 3; pos += c3;
        base += __popcll(b0) + __popcll(b1) + __popcll(b2) + __popcll(b3);
    }
    if (lane == 0) {
        cnt[r]  = base < CAP ? base : CAP;
        dinv[r] = rsqrtf((float)(base + 1));   // +1 self loop
    }
}

// ---------------------------------------------------------------------------
// Kernel 2: h1 = relu(A_norm @ w1 + b1). (measured 4.1 us)
// ---------------------------------------------------------------------------
__global__ __launch_bounds__(512) void k_spmm1(
    const float* __restrict__ w1, const float* __restrict__ b1,
    const int* __restrict__ nbr, const int* __restrict__ cnt,
    const float* __restrict__ dinv, float* __restrict__ h1)
{
    int xcd  = blockIdx.x & 7;
    int slot = blockIdx.x >> 3;
    int wid  = (xcd >> 1) * 1024 + slot * 2 + (xcd & 1);
    int g = threadIdx.x >> 7;
    int h = threadIdx.x & 127;
    int r = wid * 4 + g;
    int v = r >> 12;
    __shared__ int   s_j[4][CAP];
    __shared__ float s_w[4][CAP];
    int n = cnt[r];
    float dr = dinv[r];
    if (h < n) {
        int j = nbr[(size_t)r * CAP + h];
        s_j[g][h] = j;
        s_w[g][h] = dinv[v * NN + j];
    }
    __syncthreads();
    float acc = dr * w1[(size_t)r * HH + h];
    #pragma unroll 4
    for (int k = 0; k < n; ++k)
        acc += s_w[g][k] * w1[((size_t)(v * NN + s_j[g][k])) * HH + h];
    float val = dr * acc + b1[v * HH + h];
    h1[(size_t)r * HH + h] = val > 0.f ? val : 0.f;
}

// ---------------------------------------------------------------------------
// Kernel 3a: u = A_norm @ h1 (gather only). (measured 5.2 us)
// ---------------------------------------------------------------------------
__global__ __launch_bounds__(512) void k_gather2(
    const float* __restrict__ h1, const int* __restrict__ nbr,
    const int* __restrict__ cnt, const float* __restrict__ dinv,
    float* __restrict__ u)
{
    int xcd  = blockIdx.x & 7;
    int slot = blockIdx.x >> 3;
    int wid  = (xcd >> 1) * 1024 + slot * 2 + (xcd & 1);
    int g = threadIdx.x >> 7;
    int h = threadIdx.x & 127;
    int r = wid * 4 + g;
    int v = r >> 12;
    __shared__ int   s_j[4][CAP];
    __shared__ float s_w[4][CAP];
    int n = cnt[r];
    float dr = dinv[r];
    if (h < n) {
        int j = nbr[(size_t)r * CAP + h];
        s_j[g][h] = j;
        s_w[g][h] = dinv[v * NN + j];
    }
    __syncthreads();
    float acc = dr * h1[(size_t)r * HH + h];
    #pragma unroll 4
    for (int k = 0; k < n; ++k)
        acc += s_w[g][k] * h1[((size_t)(v * NN + s_j[g][k])) * HH + h];
    u[(size_t)r * HH + h] = dr * acc;
}

// ---------------------------------------------------------------------------
// Kernel 3b: h2 = relu(u @ w2 + b2) + per-block column partial sums.
// GR=32 (in-pipeline best; GR=16 regressed +6.6 us, R21).
// ---------------------------------------------------------------------------
__global__ __launch_bounds__(256) void k_gemm2c(
    const float* __restrict__ u, const float* __restrict__ w2,
    const float* __restrict__ b2, float* __restrict__ h2,
    float* __restrict__ part)
{
    const int bpv = NN / GR;            // 128
    int v = blockIdx.x / bpv;
    int rbase_g = blockIdx.x * GR;      // first global row
    __shared__ float s_u[GR][HH];       // 16 KB
    __shared__ float s_p[8][HH];        // 4 KB
    const float4* src = (const float4*)(u + (size_t)rbase_g * HH);
    for (int idx = threadIdx.x; idx < GR * HH / 4; idx += 256)
        ((float4*)s_u)[idx] = src[idx];
    __syncthreads();

    int r0 = (threadIdx.x >> 5) * 4;          // 0..28
    int c0 = (threadIdx.x & 31) * 4;          // 0..124
    const float* wv = w2 + (size_t)v * HH * HH;
    float acc[4][4];
    #pragma unroll
    for (int i = 0; i < 4; ++i)
        #pragma unroll
        for (int j = 0; j < 4; ++j) acc[i][j] = 0.f;
    for (int k = 0; k < HH; k += 4) {
        float4 a[4], w[4];
        #pragma unroll
        for (int i = 0; i < 4; ++i) a[i] = *(const float4*)&s_u[r0 + i][k];
        #pragma unroll
        for (int kk = 0; kk < 4; ++kk) w[kk] = *(const float4*)&wv[(size_t)(k + kk) * HH + c0];
        #pragma unroll
        for (int i = 0; i < 4; ++i)
            #pragma unroll
            for (int j = 0; j < 4; ++j) {
                acc[i][j] += a[i].x * ((const float*)&w[0])[j];
                acc[i][j] += a[i].y * ((const float*)&w[1])[j];
                acc[i][j] += a[i].z * ((const float*)&w[2])[j];
                acc[i][j] += a[i].w * ((const float*)&w[3])[j];
            }
    }
    float p[4];
    #pragma unroll
    for (int j = 0; j < 4; ++j) {
        float b = b2[v * HH + c0 + j];
        float s = 0.f;
        #pragma unroll
        for (int i = 0; i < 4; ++i) {
            float val = acc[i][j] + b;
            val = val > 0.f ? val : 0.f;
            acc[i][j] = val;
            s += val;
        }
        p[j] = s;
    }
    float* dst = h2 + (size_t)rbase_g * HH;
    #pragma unroll
    for (int i = 0; i < 4; ++i) {
        float4 o = { acc[i][0], acc[i][1], acc[i][2], acc[i][3] };
        *(float4*)&dst[(size_t)(r0 + i) * HH + c0] = o;
    }
    *(float4*)&s_p[threadIdx.x >> 5][c0] = *(float4*)p;
    __syncthreads();
    if (threadIdx.x < HH) {
        float a = 0.f;
        #pragma unroll
        for (int q = 0; q < 8; ++q) a += s_p[q][threadIdx.x];
        part[(size_t)blockIdx.x * HH + threadIdx.x] = a;
    }
}

// ---------------------------------------------------------------------------
// Kernel 4: finish summaries, attention MLP, softmax. (measured 4.9 us)
// ---------------------------------------------------------------------------
__global__ __launch_bounds__(512) void k_attn(
    const float* __restrict__ part, const float* __restrict__ wa1,
    const float* __restrict__ ba1, const float* __restrict__ wa2,
    const float* __restrict__ ba2, float* __restrict__ attn_out,
    float* __restrict__ attn_ws)
{
    __shared__ float s_sum[VV * HH];
    __shared__ float s_red[256];
    __shared__ float s_score[VV];
    {
        int v = threadIdx.x >> 7, h = threadIdx.x & 127;
        float a = 0.f;
        #pragma unroll 8
        for (int c = 0; c < CHP; ++c) a += part[(size_t)(v * CHP + c) * HH + h];
        s_sum[v * HH + h] = a * (1.0f / NN);
    }
    __syncthreads();
    if (threadIdx.x < 256) {
        int v = threadIdx.x >> 6, u = threadIdx.x & 63;
        float a = ba1[u];
        for (int k = 0; k < HH; ++k) a += s_sum[v * HH + k] * wa1[k * 64 + u];
        s_red[threadIdx.x] = tanhf(a) * wa2[u];
    }
    __syncthreads();
    if (threadIdx.x < VV) {
        float sc = ba2[0];
        for (int uu = 0; uu < 64; ++uu) sc += s_red[threadIdx.x * 64 + uu];
        s_score[threadIdx.x] = sc;
    }
    __syncthreads();
    if (threadIdx.x == 0) {
        float m = s_score[0];
        for (int i = 1; i < VV; ++i) m = fmaxf(m, s_score[i]);
        float e[VV], den = 0.f;
        for (int i = 0; i < VV; ++i) { e[i] = __expf(s_score[i] - m); den += e[i]; }
        for (int i = 0; i < VV; ++i) {
            float av = e[i] / den;
            attn_out[i] = av;
            attn_ws[i]  = av;
        }
    }
}

// ---------------------------------------------------------------------------
// Kernel 5: fusion MLP v5 (best measured: 28.7 us; v3/v6/v7 levers refuted).
// ---------------------------------------------------------------------------
__global__ __launch_bounds__(512) void k_fusion5(
    const float* __restrict__ h2, const float* __restrict__ attn_ws,
    const float* __restrict__ wf1, const float* __restrict__ bf1,
    const float* __restrict__ wf2, const float* __restrict__ bf2,
    float* __restrict__ fused)
{
    __shared__ float s_in[FV][516];          // 33 KB
    __shared__ float s_pt[4][FV][256];       // 64 KB
    __shared__ float s_hid[FV][260];         // 16.6 KB
    float (*s_p2)[FV][128] = (float (*)[FV][128])&s_pt[0][0][0];

    int nbase = blockIdx.x * FV;
    int wv   = threadIdx.x >> 6;
    int lane = threadIdx.x & 63;
    int rh = wv & 1;
    int ks = wv >> 1;

    float at[VV];
    #pragma unroll
    for (int v = 0; v < VV; ++v) at[v] = attn_ws[v];

    for (int idx = threadIdx.x; idx < FV * 128; idx += 512) {
        int r = idx >> 7, c4 = idx & 127, v = c4 >> 5, h4 = c4 & 31;
        const float4* srcr = (const float4*)(h2 + ((size_t)v * NN + nbase + r) * HH);
        float4 x = srcr[h4];
        float s = at[v];
        x.x *= s; x.y *= s; x.z *= s; x.w *= s;
        *(float4*)&s_in[r][c4 * 4] = x;
    }
    __syncthreads();

    {
        int col = lane * 4;
        int r0  = rh * 8;
        int k0  = ks * 128;
        float acc[8][4];
        #pragma unroll
        for (int i = 0; i < 8; ++i) { acc[i][0] = acc[i][1] = acc[i][2] = acc[i][3] = 0.f; }
        const float* wrow = wf1 + (size_t)k0 * 256 + col;
        for (int kk = 0; kk < 128; kk += 4) {
            float4 w0 = *(const float4*)(wrow);
            float4 w1 = *(const float4*)(wrow + 256);
            float4 w2 = *(const float4*)(wrow + 512);
            float4 w3 = *(const float4*)(wrow + 768);
            wrow += 1024;
            #pragma unroll
            for (int i = 0; i < 8; ++i) {
                float4 a = *(const float4*)&s_in[r0 + i][k0 + kk];
                acc[i][0] += a.x * w0.x + a.y * w1.x + a.z * w2.x + a.w * w3.x;
                acc[i][1] += a.x * w0.y + a.y * w1.y + a.z * w2.y + a.w * w3.y;
                acc[i][2] += a.x * w0.z + a.y * w1.z + a.z * w2.z + a.w * w3.z;
                acc[i][3] += a.x * w0.w + a.y * w1.w + a.z * w2.w + a.w * w3.w;
            }
        }
        #pragma unroll
        for (int i = 0; i < 8; ++i)
            *(float4*)&s_pt[ks][r0 + i][col] = *(float4*)&acc[i][0];
    }
    __syncthreads();

    {
        int c0 = (threadIdx.x & 63) * 4;
        int rr = threadIdx.x >> 6;
        #pragma unroll
        for (int p = 0; p < 2; ++p) {
            int row = p * 8 + rr;
            float4 s0 = *(float4*)&s_pt[0][row][c0];
            float4 s1 = *(float4*)&s_pt[1][row][c0];
            float4 s2 = *(float4*)&s_pt[2][row][c0];
            float4 s3 = *(float4*)&s_pt[3][row][c0];
            float4 b  = *(const float4*)&bf1[c0];
            float4 o;
            o.x = s0.x + s1.x + s2.x + s3.x + b.x;
            o.y = s0.y + s1.y + s2.y + s3.y + b.y;
            o.z = s0.z + s1.z + s2.z + s3.z + b.z;
            o.w = s0.w + s1.w + s2.w + s3.w + b.w;
            o.x = o.x > 0.f ? o.x : 0.f;
            o.y = o.y > 0.f ? o.y : 0.f;
            o.z = o.z > 0.f ? o.z : 0.f;
            o.w = o.w > 0.f ? o.w : 0.f;
            *(float4*)&s_hid[row][c0] = o;
        }
    }
    __syncthreads();

    {
        int col = lane * 2;
        int r0  = rh * 8;
        int k0  = ks * 64;
        float acc[8][2];
        #pragma unroll
        for (int i = 0; i < 8; ++i) { acc[i][0] = 0.f; acc[i][1] = 0.f; }
        const float* wrow = wf2 + (size_t)k0 * 128 + col;
        for (int kk = 0; kk < 64; kk += 4) {
            float2 w0 = *(const float2*)(wrow);
            float2 w1 = *(const float2*)(wrow + 128);
            float2 w2 = *(const float2*)(wrow + 256);
            float2 w3 = *(const float2*)(wrow + 384);
            wrow += 512;
            #pragma unroll
            for (int i = 0; i < 8; ++i) {
                float4 a = *(const float4*)&s_hid[r0 + i][k0 + kk];
                acc[i][0] += a.x * w0.x + a.y * w1.x + a.z * w2.x + a.w * w3.x;
                acc[i][1] += a.x * w0.y + a.y * w1.y + a.z * w2.y + a.w * w3.y;
            }
        }
        #pragma unroll
        for (int i = 0; i < 8; ++i)
            *(float2*)&s_p2[ks][r0 + i][col] = *(float2*)&acc[i][0];
    }
    __syncthreads();

    {
        int c0  = (threadIdx.x & 31) * 4;
        int row = threadIdx.x >> 5;
        float4 s0 = *(float4*)&s_p2[0][row][c0];
        float4 s1 = *(float4*)&s_p2[1][row][c0];
        float4 s2 = *(float4*)&s_p2[2][row][c0];
        float4 s3 = *(float4*)&s_p2[3][row][c0];
        float4 b  = *(const float4*)&bf2[c0];
        float4 o;
        o.x = s0.x + s1.x + s2.x + s3.x + b.x;
        o.y = s0.y + s1.y + s2.y + s3.y + b.y;
        o.z = s0.z + s1.z + s2.z + s3.z + b.z;
        o.w = s0.w + s1.w + s2.w + s3.w + b.w;
        *(float4*)&fused[(size_t)(nbase + row) * HH + c0] = o;
    }
}

// ---------------------------------------------------------------------------
// FINAL CONFIG: exact R14 best (128.9 us). Revert of GR16 regression.
// ---------------------------------------------------------------------------
extern "C" void kernel_launch(void* const* d_in, const int* in_sizes, int n_in,
                              void* d_out, int out_size, void* d_ws, size_t ws_size,
                              hipStream_t stream)
{
    const float* adjs = (const float*)d_in[0];
    const float* w1   = (const float*)d_in[1];
    const float* b1   = (const float*)d_in[2];
    const float* w2   = (const float*)d_in[3];
    const float* b2   = (const float*)d_in[4];
    const float* wa1  = (const float*)d_in[5];
    const float* ba1  = (const float*)d_in[6];
    const float* wa2  = (const float*)d_in[7];
    const float* ba2  = (const float*)d_in[8];
    const float* wf1  = (const float*)d_in[9];
    const float* bf1  = (const float*)d_in[10];
    const float* wf2  = (const float*)d_in[11];
    const float* bf2  = (const float*)d_in[12];

    float* out   = (float*)d_out;
    float* fused = out;                        // [N, 128]
    float* attn  = out + (size_t)NN * HH;      // [V]
    float* h2    = attn + VV;                  // [V, N, H]

    char* w = (char*)d_ws;
    int*   nbr    = (int*)w;    w += (size_t)VV * NN * CAP * sizeof(int);
    int*   cnt    = (int*)w;    w += (size_t)VV * NN * sizeof(int);
    float* dinv   = (float*)w;  w += (size_t)VV * NN * sizeof(float);
    float* h1     = (float*)w;  w += (size_t)VV * NN * HH * sizeof(float);
    float* u      = (float*)w;  w += (size_t)VV * NN * HH * sizeof(float);
    float* part   = (float*)w;  w += (size_t)VV * CHP * HH * sizeof(float);
    float* attnws = (float*)w;  w += 256;

    k_build_csr<<<VV * NN / 4, 256, 0, stream>>>(adjs, nbr, cnt, dinv);
    k_spmm1<<<VV * NN / 4, 512, 0, stream>>>(w1, b1, nbr, cnt, dinv, h1);
    k_gather2<<<VV * NN / 4, 512, 0, stream>>>(h1, nbr, cnt, dinv, u);
    k_gemm2c<<<VV * NN / GR, 256, 0, stream>>>(u, w2, b2, h2, part);
    k_attn<<<1, 512, 0, stream>>>(part, wa1, ba1, wa2, ba2, attn, attnws);
    k_fusion5<<<NN / FV, 512, 0, stream>>>(h2, attnws, wf1, bf1, wf2, bf2, fused);
}